// Round 3
// baseline (1796.678 us; speedup 1.0000x reference)
//
#include <hip/hip_runtime.h>
#include <cstddef>

#define HID 17
#define KNUM 4
#define BATCH 16
#define CIN 64
#define COUT 64
#define HH 256
#define WW 256

// ---------------- kernel 1: global average pool ----------------
__global__ __launch_bounds__(256) void pool_kernel(const float* __restrict__ x,
                                                   float* __restrict__ pooled) {
    int bc = blockIdx.x;  // b*CIN + c
    const float4* p = (const float4*)(x + (size_t)bc * (HH * WW));
    float s = 0.f;
    for (int idx = threadIdx.x; idx < HH * WW / 4; idx += 256) {
        float4 v = p[idx];
        s += v.x + v.y + v.z + v.w;
    }
    #pragma unroll
    for (int off = 32; off > 0; off >>= 1) s += __shfl_down(s, off, 64);
    __shared__ float wsum[4];
    int lane = threadIdx.x & 63, wv = threadIdx.x >> 6;
    if (lane == 0) wsum[wv] = s;
    __syncthreads();
    if (threadIdx.x == 0) {
        float t = wsum[0] + wsum[1] + wsum[2] + wsum[3];
        pooled[bc] = t * (1.0f / (HH * WW));
    }
}

// ---------------- kernel 2: attention + aggregated bias ----------------
__global__ __launch_bounds__(256) void att_kernel(const float* __restrict__ pooled,
                                                  const float* __restrict__ fc1_w,
                                                  const float* __restrict__ fc2_w,
                                                  const float* __restrict__ fc2_b,
                                                  const float* __restrict__ bias_k,
                                                  float* __restrict__ att,
                                                  float* __restrict__ agg_b) {
    __shared__ float h_lds[BATCH][HID];
    __shared__ float logit_lds[BATCH][KNUM];
    __shared__ float att_lds[BATCH][KNUM];
    for (int idx = threadIdx.x; idx < BATCH * HID; idx += 256) {
        int b = idx / HID, j = idx - b * HID;
        float s = 0.f;
        for (int c = 0; c < CIN; ++c) s += pooled[b * CIN + c] * fc1_w[j * CIN + c];
        h_lds[b][j] = (s >= 0.f) ? s : 0.2f * s;
    }
    __syncthreads();
    if (threadIdx.x < BATCH * KNUM) {
        int b = threadIdx.x / KNUM, k = threadIdx.x - b * KNUM;
        float s = fc2_b[k];
        for (int j = 0; j < HID; ++j) s += h_lds[b][j] * fc2_w[k * HID + j];
        logit_lds[b][k] = s * (1.0f / 34.0f);
    }
    __syncthreads();
    if (threadIdx.x < BATCH) {
        int b = threadIdx.x;
        float m = logit_lds[b][0];
        for (int k = 1; k < KNUM; ++k) m = fmaxf(m, logit_lds[b][k]);
        float e[KNUM];
        float sum = 0.f;
        for (int k = 0; k < KNUM; ++k) { e[k] = expf(logit_lds[b][k] - m); sum += e[k]; }
        float inv = 1.0f / sum;
        for (int k = 0; k < KNUM; ++k) {
            float a = e[k] * inv;
            att_lds[b][k] = a;
            att[b * KNUM + k] = a;
        }
    }
    __syncthreads();
    for (int idx = threadIdx.x; idx < BATCH * COUT; idx += 256) {
        int b = idx / COUT, o = idx - b * COUT;
        float s = 0.f;
        for (int k = 0; k < KNUM; ++k) s += att_lds[b][k] * bias_k[k * COUT + o];
        agg_b[idx] = s;
    }
}

// ---------------- kernel 3: aggregated weights ----------------
__global__ __launch_bounds__(256) void aggw_kernel(const float* __restrict__ att,
                                                   const float* __restrict__ weight,
                                                   float* __restrict__ agg_w) {
    const int per_b = COUT * CIN * 9;  // 36864
    const int total = BATCH * per_b;   // 589824
    for (int e = blockIdx.x * 256 + threadIdx.x; e < total; e += gridDim.x * 256) {
        int b = e / per_b, r = e - b * per_b;
        float s = 0.f;
        #pragma unroll
        for (int k = 0; k < KNUM; ++k) s += att[b * KNUM + k] * weight[k * per_b + r];
        agg_w[e] = s;
    }
}

// ---------------- kernel 4: direct conv ----------------
// block = 256 threads; output tile = 16 o x 16 h x 64 w
// thread: wl = tid&63 (w), hq = tid>>6 (h-quad); 4 px per thread, 16 o per thread
#define OC 16
#define HT 16
#define WT 64

__global__ __launch_bounds__(256) void conv_kernel(const float* __restrict__ x,
                                                   const float* __restrict__ agg_w,
                                                   const float* __restrict__ agg_b,
                                                   float* __restrict__ out) {
    __shared__ float xt[18][66];   // x tile + halo for one input channel
    __shared__ float wt[OC][12];   // 9 weights padded to 12 (16B-aligned rows)

    const int o0 = blockIdx.x * OC;
    const int h0 = (blockIdx.y >> 2) * HT;
    const int w0 = (blockIdx.y & 3) * WT;
    const int b = blockIdx.z;
    const int wl = threadIdx.x & 63;
    const int hq = threadIdx.x >> 6;

    float acc[OC][4];
    #pragma unroll
    for (int o = 0; o < OC; ++o)
        #pragma unroll
        for (int p = 0; p < 4; ++p) acc[o][p] = 0.f;

    for (int i = 0; i < CIN; ++i) {
        __syncthreads();
        // stage x tile for channel i
        const float* xp = x + (size_t)(b * CIN + i) * (HH * WW);
        for (int idx = threadIdx.x; idx < 18 * 66; idx += 256) {
            int r = idx / 66, c = idx - r * 66;
            int gh = h0 - 1 + r, gw = w0 - 1 + c;
            float v = 0.f;
            if ((unsigned)gh < HH && (unsigned)gw < WW) v = xp[gh * WW + gw];
            xt[r][c] = v;
        }
        // stage weights for channel i (16 o x 9 taps)
        if (threadIdx.x < OC * 9) {
            int o = threadIdx.x / 9, t = threadIdx.x - o * 9;
            wt[o][t] = agg_w[((size_t)(b * COUT + o0 + o) * CIN + i) * 9 + t];
        }
        __syncthreads();

        // per-thread x registers: rows hq*4 .. hq*4+5, cols wl .. wl+2
        float xr[6][3];
        #pragma unroll
        for (int rr = 0; rr < 6; ++rr)
            #pragma unroll
            for (int cc = 0; cc < 3; ++cc)
                xr[rr][cc] = xt[hq * 4 + rr][wl + cc];

        #pragma unroll
        for (int o = 0; o < OC; ++o) {
            float wv[9];
            #pragma unroll
            for (int t = 0; t < 9; ++t) wv[t] = wt[o][t];
            #pragma unroll
            for (int p = 0; p < 4; ++p) {
                float s = acc[o][p];
                #pragma unroll
                for (int dh = 0; dh < 3; ++dh)
                    #pragma unroll
                    for (int dw = 0; dw < 3; ++dw)
                        s = fmaf(xr[p + dh][dw], wv[dh * 3 + dw], s);
                acc[o][p] = s;
            }
        }
    }

    // epilogue: add bias, store
    #pragma unroll
    for (int o = 0; o < OC; ++o) {
        float bb = agg_b[b * COUT + o0 + o];
        #pragma unroll
        for (int p = 0; p < 4; ++p) {
            int h = h0 + hq * 4 + p;
            out[((size_t)(b * COUT + o0 + o) * HH + h) * WW + w0 + wl] = acc[o][p] + bb;
        }
    }
}

extern "C" void kernel_launch(void* const* d_in, const int* in_sizes, int n_in,
                              void* d_out, int out_size, void* d_ws, size_t ws_size,
                              hipStream_t stream) {
    const float* x      = (const float*)d_in[0];
    const float* fc1_w  = (const float*)d_in[1];
    const float* fc2_w  = (const float*)d_in[2];
    const float* fc2_b  = (const float*)d_in[3];
    const float* weight = (const float*)d_in[4];
    const float* bias_k = (const float*)d_in[5];
    float* out = (float*)d_out;
    float* ws  = (float*)d_ws;

    float* pooled = ws;           // 1024
    float* att    = ws + 1024;    // 64
    float* agg_b  = ws + 1088;    // 1024
    float* agg_w  = ws + 2112;    // 589824

    pool_kernel<<<dim3(BATCH * CIN), dim3(256), 0, stream>>>(x, pooled);
    att_kernel<<<dim3(1), dim3(256), 0, stream>>>(pooled, fc1_w, fc2_w, fc2_b, bias_k, att, agg_b);
    aggw_kernel<<<dim3(256), dim3(256), 0, stream>>>(att, weight, agg_w);
    conv_kernel<<<dim3(4, 64, 16), dim3(256), 0, stream>>>(x, agg_w, agg_b, out);
}

// Round 4
// 714.491 us; speedup vs baseline: 2.5146x; 2.5146x over previous
//
#include <hip/hip_runtime.h>
#include <cstddef>
#include <cstdint>

#define BATCH 16
#define CIN 64
#define COUT 64
#define HH 256
#define WW 256
#define HID 17
#define KNUM 4

// conv tile: 8 rows x 32 cols per block, 4 waves, each wave = 2 rows x 32 cols x all 64 o
#define TH 8
#define TW 32
#define XROWS (TH + 2)
#define XCOLS (TW + 2)
#define NPIX (XROWS * XCOLS)   // 340
#define XSTR 72                // shorts per pixel (64 ch + 8 pad) = 144 B: 16B-aligned, not 128B-multiple -> conflict-free b128 reads
#define XSTR32 36

typedef __attribute__((ext_vector_type(4))) float f32x4;
typedef __attribute__((ext_vector_type(8))) short s16x8;

static __device__ __forceinline__ unsigned short f2bf(float f) {
    unsigned u = __builtin_bit_cast(unsigned, f);
    u += 0x7FFFu + ((u >> 16) & 1u);   // RNE
    return (unsigned short)(u >> 16);
}

// ---------------- kernel 1: global average pool ----------------
__global__ __launch_bounds__(256) void pool_kernel(const float* __restrict__ x,
                                                   float* __restrict__ pooled) {
    int bc = blockIdx.x;
    const float4* p = (const float4*)(x + (size_t)bc * (HH * WW));
    float s = 0.f;
    for (int idx = threadIdx.x; idx < HH * WW / 4; idx += 256) {
        float4 v = p[idx];
        s += v.x + v.y + v.z + v.w;
    }
    #pragma unroll
    for (int off = 32; off > 0; off >>= 1) s += __shfl_down(s, off, 64);
    __shared__ float wsum[4];
    int lane = threadIdx.x & 63, wvi = threadIdx.x >> 6;
    if (lane == 0) wsum[wvi] = s;
    __syncthreads();
    if (threadIdx.x == 0) {
        float t = wsum[0] + wsum[1] + wsum[2] + wsum[3];
        pooled[bc] = t * (1.0f / (HH * WW));
    }
}

// ---------------- kernel 2: attention + aggregated bias ----------------
__global__ __launch_bounds__(256) void att_kernel(const float* __restrict__ pooled,
                                                  const float* __restrict__ fc1_w,
                                                  const float* __restrict__ fc2_w,
                                                  const float* __restrict__ fc2_b,
                                                  const float* __restrict__ bias_k,
                                                  float* __restrict__ att,
                                                  float* __restrict__ agg_b) {
    __shared__ float h_lds[BATCH][HID];
    __shared__ float logit_lds[BATCH][KNUM];
    __shared__ float att_lds[BATCH][KNUM];
    for (int idx = threadIdx.x; idx < BATCH * HID; idx += 256) {
        int b = idx / HID, j = idx - b * HID;
        float s = 0.f;
        for (int c = 0; c < CIN; ++c) s += pooled[b * CIN + c] * fc1_w[j * CIN + c];
        h_lds[b][j] = (s >= 0.f) ? s : 0.2f * s;
    }
    __syncthreads();
    if (threadIdx.x < BATCH * KNUM) {
        int b = threadIdx.x / KNUM, k = threadIdx.x - b * KNUM;
        float s = fc2_b[k];
        for (int j = 0; j < HID; ++j) s += h_lds[b][j] * fc2_w[k * HID + j];
        logit_lds[b][k] = s * (1.0f / 34.0f);
    }
    __syncthreads();
    if (threadIdx.x < BATCH) {
        int b = threadIdx.x;
        float m = logit_lds[b][0];
        for (int k = 1; k < KNUM; ++k) m = fmaxf(m, logit_lds[b][k]);
        float e[KNUM];
        float sum = 0.f;
        for (int k = 0; k < KNUM; ++k) { e[k] = expf(logit_lds[b][k] - m); sum += e[k]; }
        float inv = 1.0f / sum;
        for (int k = 0; k < KNUM; ++k) {
            float a = e[k] * inv;
            att_lds[b][k] = a;
            att[b * KNUM + k] = a;
        }
    }
    __syncthreads();
    for (int idx = threadIdx.x; idx < BATCH * COUT; idx += 256) {
        int b = idx / COUT, o = idx - b * COUT;
        float s = 0.f;
        for (int k = 0; k < KNUM; ++k) s += att_lds[b][k] * bias_k[k * COUT + o];
        agg_b[idx] = s;
    }
}

// ---------------- kernel 3: aggregate + pack weights to bf16 [b][t][o][i/2] ----------------
__global__ __launch_bounds__(256) void aggw_kernel(const float* __restrict__ att,
                                                   const float* __restrict__ weight,
                                                   unsigned* __restrict__ agg_wb) {
    const int total = BATCH * 9 * COUT * (CIN / 2);  // 294912 u32
    const size_t kstride = (size_t)COUT * CIN * 9;
    for (int d = blockIdx.x * 256 + threadIdx.x; d < total; d += gridDim.x * 256) {
        int b = d / (9 * COUT * 32);
        int rem = d - b * (9 * COUT * 32);
        int t = rem / (COUT * 32);
        int rem2 = rem - t * (COUT * 32);
        int o = rem2 >> 5;
        int ip = rem2 & 31;
        int i = ip * 2;
        float a0 = att[b * KNUM + 0], a1 = att[b * KNUM + 1];
        float a2 = att[b * KNUM + 2], a3 = att[b * KNUM + 3];
        // weight[k][o][i][dh][dw], t = dh*3+dw
        const float* w0 = weight + ((size_t)(o * CIN + i) * 9 + t);
        float s0 = a0 * w0[0] + a1 * w0[kstride] + a2 * w0[2 * kstride] + a3 * w0[3 * kstride];
        const float* w1 = w0 + 9;
        float s1 = a0 * w1[0] + a1 * w1[kstride] + a2 * w1[2 * kstride] + a3 * w1[3 * kstride];
        agg_wb[d] = (unsigned)f2bf(s0) | ((unsigned)f2bf(s1) << 16);
    }
}

// ---------------- kernel 4: MFMA implicit-GEMM conv ----------------
// D[o][p] = sum_t sum_i W_t[o][i] * X[i][p+shift(t)], 16x16x32 bf16 MFMA.
// A-frags (weights) read straight from global (L1/L2-resident); B-frags from LDS x tile.
__global__ __launch_bounds__(256) void conv_kernel(
    const float* __restrict__ x, const unsigned* __restrict__ agg_wb,
    const float* __restrict__ agg_b, float* __restrict__ out)
{
    __shared__ short xs[NPIX * XSTR];   // 48960 B
    unsigned* xs32 = (unsigned*)xs;

    const int tid = threadIdx.x;
    const int lane = tid & 63;
    const int wv = tid >> 6;      // wave 0..3 -> rows 2wv..2wv+1 of tile
    const int l15 = lane & 15;
    const int q = lane >> 4;      // k-block 0..3
    const int b = blockIdx.z;
    const int r0 = blockIdx.y * TH;
    const int c0 = blockIdx.x * TW;

    // ---- stage x tile: rows r0-1..r0+TH, cols c0-1..c0+TW, pixel-major channel-minor bf16 ----
    {
        const float* xb = x + (size_t)b * CIN * HH * WW;
        #pragma unroll 4
        for (int ig = 0; ig < CIN / 4; ++ig) {
            const float* p0 = xb + (size_t)(4 * ig) * (HH * WW);
            for (int pix = tid; pix < NPIX; pix += 256) {
                int r = pix / XCOLS;
                int c = pix - r * XCOLS;
                int gr = r0 - 1 + r, gc = c0 - 1 + c;
                float v0 = 0.f, v1 = 0.f, v2 = 0.f, v3 = 0.f;
                if ((unsigned)gr < HH && (unsigned)gc < WW) {
                    int off = gr * WW + gc;
                    v0 = p0[off];
                    v1 = p0[off + HH * WW];
                    v2 = p0[off + 2 * HH * WW];
                    v3 = p0[off + 3 * HH * WW];
                }
                uint2 pk;
                pk.x = (unsigned)f2bf(v0) | ((unsigned)f2bf(v1) << 16);
                pk.y = (unsigned)f2bf(v2) | ((unsigned)f2bf(v3) << 16);
                *(uint2*)(xs32 + pix * XSTR32 + ig * 2) = pk;
            }
        }
    }
    __syncthreads();   // only barrier in the kernel

    const unsigned* wb = agg_wb + (size_t)b * (9 * COUT * (CIN / 2));

    f32x4 acc[4][4];
    #pragma unroll
    for (int mt = 0; mt < 4; ++mt)
        #pragma unroll
        for (int nt = 0; nt < 4; ++nt)
            acc[mt][nt] = (f32x4){0.f, 0.f, 0.f, 0.f};

    for (int t = 0; t < 9; ++t) {
        const int dh = t / 3;
        const int dw = t - dh * 3;
        #pragma unroll
        for (int ic = 0; ic < 2; ++ic) {
            // A: lane reads W_t[o = mt*16+l15][i = ic*32 + q*8 .. +7] -> 16B global load
            s16x8 af[4];
            #pragma unroll
            for (int mt = 0; mt < 4; ++mt)
                af[mt] = *(const s16x8*)(wb + ((t * COUT + mt * 16 + l15) * 32 + ic * 16 + q * 4));
            // B: lane reads X[i = same k-slice][pix = shifted output pixel] -> ds_read_b128
            s16x8 bfr[4];
            #pragma unroll
            for (int nt = 0; nt < 4; ++nt) {
                int rr = nt >> 1, cc = nt & 1;
                int pix = (2 * wv + rr + dh) * XCOLS + cc * 16 + l15 + dw;
                bfr[nt] = *(const s16x8*)(xs + pix * XSTR + ic * 32 + q * 8);
            }
            #pragma unroll
            for (int mt = 0; mt < 4; ++mt)
                #pragma unroll
                for (int nt = 0; nt < 4; ++nt)
                    acc[mt][nt] = __builtin_amdgcn_mfma_f32_16x16x32_bf16(af[mt], bfr[nt], acc[mt][nt], 0, 0, 0);
        }
    }

    // ---- epilogue: D col = lane&15 (pixel), row = 4*(lane>>4)+reg (o) [m89-verified] ----
    const float* bbp = agg_b + b * COUT;
    float* op = out + (size_t)b * COUT * HH * WW;
    #pragma unroll
    for (int mt = 0; mt < 4; ++mt) {
        #pragma unroll
        for (int rg = 0; rg < 4; ++rg) {
            int o = mt * 16 + q * 4 + rg;
            float bv = bbp[o];
            #pragma unroll
            for (int nt = 0; nt < 4; ++nt) {
                int rr = nt >> 1, cc = nt & 1;
                int row = r0 + 2 * wv + rr;
                int col = c0 + cc * 16 + l15;
                op[((size_t)o * HH + row) * WW + col] = acc[mt][nt][rg] + bv;
            }
        }
    }
}

extern "C" void kernel_launch(void* const* d_in, const int* in_sizes, int n_in,
                              void* d_out, int out_size, void* d_ws, size_t ws_size,
                              hipStream_t stream) {
    const float* x      = (const float*)d_in[0];
    const float* fc1_w  = (const float*)d_in[1];
    const float* fc2_w  = (const float*)d_in[2];
    const float* fc2_b  = (const float*)d_in[3];
    const float* weight = (const float*)d_in[4];
    const float* bias_k = (const float*)d_in[5];
    float* out = (float*)d_out;
    float* ws  = (float*)d_ws;

    float*    pooled = ws;                       // 1024 f32
    float*    att    = ws + 1024;                // 64 f32
    float*    agg_b  = ws + 1088;                // 1024 f32
    unsigned* agg_wb = (unsigned*)(ws + 2112);   // 294912 u32 (bf16 pairs), 16B-aligned offset

    pool_kernel<<<dim3(BATCH * CIN), dim3(256), 0, stream>>>(x, pooled);
    att_kernel<<<dim3(1), dim3(256), 0, stream>>>(pooled, fc1_w, fc2_w, fc2_b, bias_k, att, agg_b);
    aggw_kernel<<<dim3(1152), dim3(256), 0, stream>>>(att, weight, agg_wb);
    conv_kernel<<<dim3(WW / TW, HH / TH, BATCH), dim3(256), 0, stream>>>(x, agg_wb, agg_b, out);
}